// Round 4
// baseline (10201.144 us; speedup 1.0000x reference)
//
#include <hip/hip_runtime.h>
#include <hip/hip_bf16.h>
#include <math.h>

#define TCc 200
#define TDc 50
#define BATCH 256
#define Ec 300
#define Hc 512
#define VOC 10000

typedef __bf16 bf16x8 __attribute__((ext_vector_type(8)));
typedef float f32x4 __attribute__((ext_vector_type(4)));

__device__ __forceinline__ float sigf(float x) { return 1.f / (1.f + expf(-x)); }

__device__ __forceinline__ unsigned short f2bf(float f) {
  unsigned u = __float_as_uint(f);
  unsigned r = (u + 0x7FFFu + ((u >> 16) & 1u)) >> 16;  // RNE
  return (unsigned short)r;
}

__global__ __launch_bounds__(256) void zero_kernel(float* p, int n) {
  int i = blockIdx.x * 256 + threadIdx.x;
  if (i < n) p[i] = 0.f;
}

// Convert Whh (4H,H) fp32 -> fragment-ordered bf16 for mfma_f32_16x16x32_bf16.
// Layout: [cg 32][kc 16][s 4][lane 64][j 8] bf16, packed as u32 pairs.
// col c' = cg*64 + s*16 + (lane&15); unit u = c'>>2, gate g = c'&3;
// k = kc*32 + (lane>>4)*8 + j.
__global__ __launch_bounds__(256) void convert_whh_kernel(
    const float* __restrict__ W, unsigned* __restrict__ Bfg)
{
  int e = blockIdx.x * 256 + threadIdx.x;  // u32 index, 524288 total
  int jp = e & 3;
  int lane = (e >> 2) & 63;
  int s = (e >> 8) & 3;
  int kc = (e >> 10) & 15;
  int cg = e >> 14;
  int cp = (cg << 6) + (s << 4) + (lane & 15);
  int u = cp >> 2, g = cp & 3;
  int k = (kc << 5) + ((lane >> 4) << 3) + (jp << 1);
  const float* src = &W[((size_t)(g << 9) + u) * Hc + k];
  unsigned lo = f2bf(src[0]), hi = f2bf(src[1]);
  Bfg[e] = lo | (hi << 16);
}

// ---------------- generic 64x64-tile fp32 GEMM: out = act(A @ Bw^T + bias) ----------------
template<int ACT, int REDUCE>
__global__ __launch_bounds__(256) void gemm64_kernel(
    const float* __restrict__ A, const float* __restrict__ Bw,
    const float* __restrict__ bias, float* __restrict__ C,
    const float* __restrict__ sW, float* __restrict__ partial,
    int M, int N, int K)
{
  const int r0 = blockIdx.x * 64;
  const int n0 = blockIdx.y * 64;
  const int tid = threadIdx.x;
  const int tu = tid & 15;
  const int tm = tid >> 4;
  __shared__ float As[32][68];
  __shared__ float Bs[32][68];
  __shared__ float red[64][17];

  float acc[4][4] = {};
  const int nk = (K + 31) >> 5;
  for (int s = 0; s < nk; ++s) {
    const int k0 = s << 5;
    #pragma unroll
    for (int i = 0; i < 2; ++i) {
      int lin = tid + (i << 8);
      int kq = lin & 7, m = lin >> 3;
      int k = k0 + (kq << 2);
      int r = r0 + m; if (r >= M) r = M - 1;
      float4 va = {0.f, 0.f, 0.f, 0.f}, vb = {0.f, 0.f, 0.f, 0.f};
      if (k < K) {
        va = *(const float4*)&A[(size_t)r * K + k];
        vb = *(const float4*)&Bw[(size_t)(n0 + m) * K + k];
      }
      As[(kq << 2) + 0][m] = va.x; As[(kq << 2) + 1][m] = va.y;
      As[(kq << 2) + 2][m] = va.z; As[(kq << 2) + 3][m] = va.w;
      Bs[(kq << 2) + 0][m] = vb.x; Bs[(kq << 2) + 1][m] = vb.y;
      Bs[(kq << 2) + 2][m] = vb.z; Bs[(kq << 2) + 3][m] = vb.w;
    }
    __syncthreads();
    #pragma unroll
    for (int kk = 0; kk < 32; ++kk) {
      float4 a = *(const float4*)&As[kk][tm << 2];
      float4 b = *(const float4*)&Bs[kk][tu << 2];
      acc[0][0] = fmaf(a.x, b.x, acc[0][0]); acc[0][1] = fmaf(a.x, b.y, acc[0][1]);
      acc[0][2] = fmaf(a.x, b.z, acc[0][2]); acc[0][3] = fmaf(a.x, b.w, acc[0][3]);
      acc[1][0] = fmaf(a.y, b.x, acc[1][0]); acc[1][1] = fmaf(a.y, b.y, acc[1][1]);
      acc[1][2] = fmaf(a.y, b.z, acc[1][2]); acc[1][3] = fmaf(a.y, b.w, acc[1][3]);
      acc[2][0] = fmaf(a.z, b.x, acc[2][0]); acc[2][1] = fmaf(a.z, b.y, acc[2][1]);
      acc[2][2] = fmaf(a.z, b.z, acc[2][2]); acc[2][3] = fmaf(a.z, b.w, acc[2][3]);
      acc[3][0] = fmaf(a.w, b.x, acc[3][0]); acc[3][1] = fmaf(a.w, b.y, acc[3][1]);
      acc[3][2] = fmaf(a.w, b.z, acc[3][2]); acc[3][3] = fmaf(a.w, b.w, acc[3][3]);
    }
    __syncthreads();
  }

  if (REDUCE) {
    float bj[4], wj[4];
    #pragma unroll
    for (int j = 0; j < 4; ++j) {
      int n = n0 + (tu << 2) + j;
      bj[j] = bias[n]; wj[j] = sW[n];
    }
    float p[4] = {0.f, 0.f, 0.f, 0.f};
    #pragma unroll
    for (int i = 0; i < 4; ++i)
      #pragma unroll
      for (int j = 0; j < 4; ++j)
        p[i] = fmaf(tanhf(acc[i][j] + bj[j]), wj[j], p[i]);
    #pragma unroll
    for (int i = 0; i < 4; ++i) red[(tm << 2) + i][tu] = p[i];
    __syncthreads();
    if (tid < 64) {
      int r = r0 + tid;
      if (r < M) {
        float s = 0.f;
        #pragma unroll
        for (int q = 0; q < 16; ++q) s += red[tid][q];
        partial[(size_t)blockIdx.y * M + r] = s;
      }
    }
  } else {
    float bj[4];
    #pragma unroll
    for (int j = 0; j < 4; ++j) bj[j] = bias ? bias[n0 + (tu << 2) + j] : 0.f;
    #pragma unroll
    for (int i = 0; i < 4; ++i) {
      int r = r0 + (tm << 2) + i;
      if (r < M) {
        float4 v;
        v.x = acc[i][0] + bj[0]; v.y = acc[i][1] + bj[1];
        v.z = acc[i][2] + bj[2]; v.w = acc[i][3] + bj[3];
        if (ACT) { v.x = tanhf(v.x); v.y = tanhf(v.y); v.z = tanhf(v.z); v.w = tanhf(v.w); }
        *(float4*)&C[(size_t)r * N + n0 + (tu << 2)] = v;
      }
    }
  }
}

// ---------------- persistent MFMA LSTM with rowgroup software barrier ----------------
// 256 blocks = 8 rowgroups x 32 colgroups. Block owns ROWS batch rows x 16 units (x4 gates
// = 64 weight cols). Whh slice = fragment-ordered bf16 in LDS (64KB). h exchanged as bf16
// through global; barrier spans only the 32 blocks of a rowgroup (h dependency is row-local).
__device__ __forceinline__ void group_barrier(unsigned* cnt, unsigned target) {
  __threadfence();
  __syncthreads();
  if (threadIdx.x == 0) {
    __hip_atomic_fetch_add(cnt, 1u, __ATOMIC_RELEASE, __HIP_MEMORY_SCOPE_AGENT);
    unsigned v;
    do {
      v = __hip_atomic_load(cnt, __ATOMIC_ACQUIRE, __HIP_MEMORY_SCOPE_AGENT);
    } while (v < target);
  }
  __syncthreads();
}

struct PArgs {
  const unsigned* Bfg_tok; const unsigned* Bfg_desc;
  const float* tokproj; const float* descproj;
  const int* tokens; const int* desc_anchor; const int* desc_neg;
  const int* desc_anchor_len; const int* desc_neg_len;
  const float* tok_bih; const float* tok_bhh;
  const float* desc_bih; const float* desc_bhh;
  unsigned short* hA; unsigned short* hB; unsigned short* hC; unsigned short* hD;
  float* feat; float* finals;
  unsigned* cnt;
};

template<int ROWS, bool IS_TOK>
__device__ void lstm_phase_mfma(
    unsigned* Bf_lds, float* gsum,
    const unsigned* __restrict__ Bfg, const float* __restrict__ xproj,
    const int* __restrict__ idsA, const int* __restrict__ idsB,
    const int* __restrict__ lenA, const int* __restrict__ lenB, int T,
    const float* __restrict__ bih, const float* __restrict__ bhh,
    unsigned short* __restrict__ h0, unsigned short* __restrict__ h1,
    float* __restrict__ feat, float* __restrict__ finals,
    unsigned* cnt_base, int& gen)
{
  constexpr int RH = ROWS / 16;   // 16-row halves (2 tok, 4 desc)
  constexpr int RP = RH;          // rows per epilogue thread
  constexpr int SPW = RH;         // col-subtiles per wave
  const int tid = threadIdx.x;
  const int bx = blockIdx.x;
  const int rg = bx >> 5;
  const int cg = bx & 31;
  const int l = tid & 63;
  const int w = tid >> 6;
  const int tu = tid & 15, tm = tid >> 4;
  const int row0 = rg * ROWS;
  unsigned* cnt = cnt_base + (rg << 4);   // 64B-spaced counters

  // load this colgroup's B-fragments (16384 u32 = 64KB) into LDS
  {
    const uint4* src = (const uint4*)(Bfg + ((size_t)cg << 14));
    uint4* dst = (uint4*)Bf_lds;
    #pragma unroll
    for (int i = 0; i < 16; ++i) dst[(i << 8) + tid] = src[(i << 8) + tid];
  }

  const int ug = (cg << 4) + tu;   // global unit
  float bsv[4];
  #pragma unroll
  for (int g = 0; g < 4; ++g) bsv[g] = bih[(g << 9) + ug] + bhh[(g << 9) + ug];

  const int* idp[RP];
  int rlen[RP];
  float cc[RP];
  #pragma unroll
  for (int p = 0; p < RP; ++p) {
    int row = row0 + tm * RP + p;
    cc[p] = 0.f;
    if (IS_TOK) { idp[p] = idsA + (size_t)row * T; rlen[p] = 0; }
    else if (row < BATCH) { idp[p] = idsA + (size_t)row * T; rlen[p] = lenA[row]; }
    else { idp[p] = idsB + (size_t)(row - BATCH) * T; rlen[p] = lenB[row - BATCH]; }
    h0[((size_t)row << 9) + ug] = 0;   // bf16 zero
  }
  ++gen; group_barrier(cnt, (unsigned)(gen * 32));

  int rh, s0;
  if constexpr (RH == 2) { rh = w >> 1; s0 = (w & 1) * 2; }
  else { rh = w; s0 = 0; }

  for (int t = 0; t < T; ++t) {
    const unsigned short* hin = (t & 1) ? h1 : h0;
    unsigned short* hout = (t & 1) ? h0 : h1;
    f32x4 acc[SPW];
    #pragma unroll
    for (int si = 0; si < SPW; ++si) acc[si] = (f32x4){0.f, 0.f, 0.f, 0.f};

    const unsigned short* arow =
        hin + (((size_t)(row0 + rh * 16 + (l & 15))) << 9) + ((l >> 4) << 3);
    const unsigned short* Bf16 = (const unsigned short*)Bf_lds;
    #pragma unroll 4
    for (int kc = 0; kc < 16; ++kc) {
      bf16x8 a = *(const bf16x8*)(arow + (kc << 5));
      #pragma unroll
      for (int si = 0; si < SPW; ++si) {
        bf16x8 b = *(const bf16x8*)(Bf16 + (size_t)((((kc << 2) + s0 + si) << 6) + l) * 8);
        acc[si] = __builtin_amdgcn_mfma_f32_16x16x32_bf16(a, b, acc[si], 0, 0, 0);
      }
    }
    // D (pre-activation gates) -> gsum[row][c'] so epilogue reads 4 gates as one float4
    #pragma unroll
    for (int si = 0; si < SPW; ++si) {
      int cb = (s0 + si) << 4;
      int rl = rh * 16 + ((l >> 4) << 2);
      #pragma unroll
      for (int r = 0; r < 4; ++r)
        gsum[(rl + r) * 68 + cb + (l & 15)] = acc[si][r];
    }
    __syncthreads();
    // epilogue: gates, c/h update, outputs
    #pragma unroll
    for (int p = 0; p < RP; ++p) {
      int rl = tm * RP + p;
      int row = row0 + rl;
      float4 gv = *(const float4*)&gsum[rl * 68 + (tu << 2)];
      int id = idp[p][t];
      const float* xp = xproj + ((size_t)id << 11);
      float gi = sigf(gv.x + xp[ug] + bsv[0]);
      float gf = sigf(gv.y + xp[Hc + ug] + bsv[1]);
      float gg = tanhf(gv.z + xp[2 * Hc + ug] + bsv[2]);
      float go = sigf(gv.w + xp[3 * Hc + ug] + bsv[3]);
      float cn = gf * cc[p] + gi * gg;
      cc[p] = cn;
      float hn = go * tanhf(cn);
      hout[((size_t)row << 9) + ug] = f2bf(hn);
      if (IS_TOK) {
        feat[((size_t)row * TCc + t) * Hc + ug] = tanhf(hn);
      } else {
        if (t == rlen[p] - 1) finals[((size_t)row << 9) + ug] = tanhf(hn);
      }
    }
    ++gen; group_barrier(cnt, (unsigned)(gen * 32));
  }
}

__global__ void __launch_bounds__(256, 1) lstm_persist_kernel(PArgs A) {
  extern __shared__ unsigned char smem[];
  unsigned* Bf = (unsigned*)smem;               // 65536 B
  float* gsum = (float*)(smem + 65536);         // 64*68*4 = 17408 B
  int gen = 0;
  lstm_phase_mfma<32, true>(Bf, gsum, A.Bfg_tok, A.tokproj, A.tokens, nullptr,
                            nullptr, nullptr, TCc, A.tok_bih, A.tok_bhh,
                            A.hA, A.hB, A.feat, nullptr, A.cnt, gen);
  lstm_phase_mfma<64, false>(Bf, gsum, A.Bfg_desc, A.descproj, A.desc_anchor, A.desc_neg,
                             A.desc_anchor_len, A.desc_neg_len, TDc, A.desc_bih, A.desc_bhh,
                             A.hC, A.hD, nullptr, A.finals, A.cnt, gen);
}

// ---------------- fallback per-step kernel (round-2, known good) ----------------
template<int HAS_XPROJ>
__global__ __launch_bounds__(256) void lstm_step2_kernel(
    const float* __restrict__ xproj_or_emb, const float* __restrict__ Wih,
    const int* __restrict__ idsA, const int* __restrict__ idsB,
    int T, int t,
    const float* __restrict__ Whh,
    const float* __restrict__ bih, const float* __restrict__ bhh,
    const float* __restrict__ h_in, const float* __restrict__ c_in,
    float* __restrict__ h_out, float* __restrict__ c_out,
    float* __restrict__ feat, float* __restrict__ finals,
    const int* __restrict__ lenA, const int* __restrict__ lenB)
{
  const int b0 = blockIdx.x * 32;
  const int u0 = blockIdx.y * 16;
  const int tid = threadIdx.x;
  const int tu = tid & 15;
  const int tm = tid >> 4;

  __shared__ float As[32][34];
  __shared__ float Bs[32][68];
  __shared__ int rows[32];

  float acc[2][4] = {};

  if (!HAS_XPROJ) {
    if (tid < 32) {
      int b = b0 + tid;
      rows[tid] = (idsB != nullptr && b >= BATCH) ? idsB[(b - BATCH) * T + t]
                                                  : idsA[b * T + t];
    }
    __syncthreads();
    for (int k0 = 0; k0 < Ec; k0 += 32) {
      {
        int kq = tid & 7, m = tid >> 3;
        int k = k0 + (kq << 2);
        float4 va = {0.f, 0.f, 0.f, 0.f};
        if (k < Ec) va = *(const float4*)&xproj_or_emb[(size_t)rows[m] * Ec + k];
        As[(kq << 2) + 0][m] = va.x; As[(kq << 2) + 1][m] = va.y;
        As[(kq << 2) + 2][m] = va.z; As[(kq << 2) + 3][m] = va.w;
      }
      #pragma unroll
      for (int i = 0; i < 2; ++i) {
        int lin = tid + (i << 8);
        int kq = lin & 7, u = (lin >> 3) & 15, g = (lin >> 7) & 3;
        int k = k0 + (kq << 2);
        float4 vb = {0.f, 0.f, 0.f, 0.f};
        if (k < Ec) vb = *(const float4*)&Wih[(size_t)((g << 9) + u0 + u) * Ec + k];
        int col = (u << 2) + g;
        Bs[(kq << 2) + 0][col] = vb.x; Bs[(kq << 2) + 1][col] = vb.y;
        Bs[(kq << 2) + 2][col] = vb.z; Bs[(kq << 2) + 3][col] = vb.w;
      }
      __syncthreads();
      #pragma unroll
      for (int kk = 0; kk < 32; ++kk) {
        float2 a = *(const float2*)&As[kk][tm << 1];
        float4 b = *(const float4*)&Bs[kk][tu << 2];
        acc[0][0] = fmaf(a.x, b.x, acc[0][0]); acc[0][1] = fmaf(a.x, b.y, acc[0][1]);
        acc[0][2] = fmaf(a.x, b.z, acc[0][2]); acc[0][3] = fmaf(a.x, b.w, acc[0][3]);
        acc[1][0] = fmaf(a.y, b.x, acc[1][0]); acc[1][1] = fmaf(a.y, b.y, acc[1][1]);
        acc[1][2] = fmaf(a.y, b.z, acc[1][2]); acc[1][3] = fmaf(a.y, b.w, acc[1][3]);
      }
      __syncthreads();
    }
  }

  for (int k0 = 0; k0 < Hc; k0 += 32) {
    {
      int kq = tid & 7, m = tid >> 3;
      float4 va = *(const float4*)&h_in[(size_t)(b0 + m) * Hc + k0 + (kq << 2)];
      As[(kq << 2) + 0][m] = va.x; As[(kq << 2) + 1][m] = va.y;
      As[(kq << 2) + 2][m] = va.z; As[(kq << 2) + 3][m] = va.w;
    }
    #pragma unroll
    for (int i = 0; i < 2; ++i) {
      int lin = tid + (i << 8);
      int kq = lin & 7, u = (lin >> 3) & 15, g = (lin >> 7) & 3;
      float4 vb = *(const float4*)&Whh[(size_t)((g << 9) + u0 + u) * Hc + k0 + (kq << 2)];
      int col = (u << 2) + g;
      Bs[(kq << 2) + 0][col] = vb.x; Bs[(kq << 2) + 1][col] = vb.y;
      Bs[(kq << 2) + 2][col] = vb.z; Bs[(kq << 2) + 3][col] = vb.w;
    }
    __syncthreads();
    #pragma unroll
    for (int kk = 0; kk < 32; ++kk) {
      float2 a = *(const float2*)&As[kk][tm << 1];
      float4 b = *(const float4*)&Bs[kk][tu << 2];
      acc[0][0] = fmaf(a.x, b.x, acc[0][0]); acc[0][1] = fmaf(a.x, b.y, acc[0][1]);
      acc[0][2] = fmaf(a.x, b.z, acc[0][2]); acc[0][3] = fmaf(a.x, b.w, acc[0][3]);
      acc[1][0] = fmaf(a.y, b.x, acc[1][0]); acc[1][1] = fmaf(a.y, b.y, acc[1][1]);
      acc[1][2] = fmaf(a.y, b.z, acc[1][2]); acc[1][3] = fmaf(a.y, b.w, acc[1][3]);
    }
    __syncthreads();
  }

  const int u = u0 + tu;
  const float bi0 = bih[u]          + bhh[u];
  const float bf0 = bih[Hc + u]     + bhh[Hc + u];
  const float bg0 = bih[2 * Hc + u] + bhh[2 * Hc + u];
  const float bo0 = bih[3 * Hc + u] + bhh[3 * Hc + u];

  #pragma unroll
  for (int p = 0; p < 2; ++p) {
    const int b = b0 + (tm << 1) + p;
    float xi = 0.f, xf = 0.f, xg = 0.f, xo = 0.f;
    if (HAS_XPROJ) {
      int id = (idsB != nullptr && b >= BATCH) ? idsB[(b - BATCH) * T + t]
                                               : idsA[b * T + t];
      const float* xp = xproj_or_emb + (size_t)id * (4 * Hc);
      xi = xp[u]; xf = xp[Hc + u]; xg = xp[2 * Hc + u]; xo = xp[3 * Hc + u];
    }
    float gi = sigf(acc[p][0] + xi + bi0);
    float gf = sigf(acc[p][1] + xf + bf0);
    float gg = tanhf(acc[p][2] + xg + bg0);
    float go = sigf(acc[p][3] + xo + bo0);
    float c_old = c_in[(size_t)b * Hc + u];
    float cn = gf * c_old + gi * gg;
    float hn = go * tanhf(cn);
    c_out[(size_t)b * Hc + u] = cn;
    h_out[(size_t)b * Hc + u] = hn;
    if (feat) feat[((size_t)b * T + t) * Hc + u] = tanhf(hn);
    if (finals) {
      int len = (b < BATCH) ? lenA[b] : lenB[b - BATCH];
      if (t == len - 1) finals[(size_t)b * Hc + u] = tanhf(hn);
    }
  }
}

__global__ __launch_bounds__(256) void score_reduce_kernel(
    const float* __restrict__ scorep, const float* __restrict__ attnS_b,
    float* __restrict__ scores, int M, int nb)
{
  int r = blockIdx.x * 256 + threadIdx.x;
  if (r < M) {
    float s = attnS_b[0];
    for (int q = 0; q < nb; ++q) s += scorep[(size_t)q * M + r];
    scores[r] = s;
  }
}

__global__ __launch_bounds__(256) void softmax_pool_kernel(
    const float* __restrict__ scores, const int* __restrict__ tok_len,
    const float* __restrict__ feat, float* __restrict__ pooled)
{
  const int b = blockIdx.x;
  const int tid = threadIdx.x;
  __shared__ float w[TCc];
  __shared__ float red[256];
  const int len = tok_len[b];

  float myv = -1e30f;
  if (tid < TCc) {
    float s = scores[b * TCc + tid];
    myv = (tid < len) ? s : -1e9f;
    w[tid] = myv;
  }
  red[tid] = myv;
  __syncthreads();
  for (int s = 128; s > 0; s >>= 1) {
    if (tid < s) red[tid] = fmaxf(red[tid], red[tid + s]);
    __syncthreads();
  }
  const float mx = red[0];
  __syncthreads();
  float e = 0.f;
  if (tid < TCc) e = expf(w[tid] - mx);
  red[tid] = e;
  __syncthreads();
  for (int s = 128; s > 0; s >>= 1) {
    if (tid < s) red[tid] += red[tid + s];
    __syncthreads();
  }
  const float sum = red[0];
  __syncthreads();
  if (tid < TCc) w[tid] = e / sum;
  __syncthreads();

  for (int h = tid; h < Hc; h += 256) {
    float acc = 0.f;
    for (int t = 0; t < TCc; ++t)
      acc = fmaf(w[t], feat[((size_t)b * TCc + t) * Hc + h], acc);
    pooled[(size_t)b * Hc + h] = acc;
  }
}

__global__ __launch_bounds__(256) void loss_kernel(
    const float* __restrict__ code, const float* __restrict__ finals, float* __restrict__ out)
{
  const int b = threadIdx.x;
  const float* cv = code + (size_t)b * Hc;
  const float* av = finals + (size_t)b * Hc;
  const float* nv = finals + (size_t)(BATCH + b) * Hc;
  float dca = 0, dcn = 0, ncc = 0, naa = 0, nnn = 0;
  for (int k = 0; k < Hc; ++k) {
    float c = cv[k], a = av[k], n = nv[k];
    dca = fmaf(c, a, dca);
    dcn = fmaf(c, n, dcn);
    ncc = fmaf(c, c, ncc);
    naa = fmaf(a, a, naa);
    nnn = fmaf(n, n, nnn);
  }
  float cos_a = dca / fmaxf(sqrtf(ncc) * sqrtf(naa), 1e-8f);
  float cos_n = dcn / fmaxf(sqrtf(ncc) * sqrtf(nnn), 1e-8f);
  float hinge = fmaxf(0.6f - cos_a + cos_n, 1e-6f);
  __shared__ float red[256];
  red[b] = hinge;
  __syncthreads();
  for (int s = 128; s > 0; s >>= 1) {
    if (b < s) red[b] += red[b + s];
    __syncthreads();
  }
  if (b == 0) out[0] = red[0] / 256.0f;
}

extern "C" void kernel_launch(void* const* d_in, const int* in_sizes, int n_in,
                              void* d_out, int out_size, void* d_ws, size_t ws_size,
                              hipStream_t stream) {
  const int* tokens          = (const int*)d_in[0];
  const int* tok_len         = (const int*)d_in[1];
  const int* desc_anchor     = (const int*)d_in[2];
  const int* desc_anchor_len = (const int*)d_in[3];
  const int* desc_neg        = (const int*)d_in[4];
  const int* desc_neg_len    = (const int*)d_in[5];
  const float* tok_emb  = (const float*)d_in[6];
  const float* tok_Wih  = (const float*)d_in[7];
  const float* tok_Whh  = (const float*)d_in[8];
  const float* tok_bih  = (const float*)d_in[9];
  const float* tok_bhh  = (const float*)d_in[10];
  const float* desc_emb = (const float*)d_in[11];
  const float* desc_Wih = (const float*)d_in[12];
  const float* desc_Whh = (const float*)d_in[13];
  const float* desc_bih = (const float*)d_in[14];
  const float* desc_bhh = (const float*)d_in[15];
  const float* attn_W   = (const float*)d_in[16];
  const float* attn_b   = (const float*)d_in[17];
  const float* attnS_W  = (const float*)d_in[18];
  const float* attnS_b  = (const float*)d_in[19];
  const float* out_W1   = (const float*)d_in[20];
  const float* out_b1   = (const float*)d_in[21];
  const float* out_W2   = (const float*)d_in[22];
  const float* out_b2   = (const float*)d_in[23];

  const size_t BH = (size_t)BATCH * Hc;           // 131072
  const size_t f_feat = (size_t)BATCH * TCc * Hc; // 26,214,400
  const size_t f_proj = (size_t)VOC * 4 * Hc;     // 20,480,000
  const size_t f_mfma = 2 * 524288 + 4 * 131072 + 1024;  // Bfg x2 + h bf16 x4 + counters = 1,573,888
  const size_t f_fb   = 12 * BH;                  // fallback h/c = 1,572,864 (aliases f_mfma)
  const size_t f_common = 2 * BH + 8 * (size_t)BATCH * TCc + (size_t)BATCH * TCc + 3 * BH;
  const size_t need_proj = (f_feat + 2 * f_proj + f_mfma + f_common) * 4;
  const bool use_proj = (ws_size >= need_proj);

  float* p = (float*)d_ws;
  size_t off = 0;
  auto alloc = [&](size_t n) { float* q = p + off; off += n; return q; };

  float* feat = alloc(f_feat);
  float* tokproj = nullptr;
  float* descproj = nullptr;
  unsigned* cnt = nullptr;
  unsigned* Bfg_tok = nullptr;
  unsigned* Bfg_desc = nullptr;
  unsigned short* hbA = nullptr; unsigned short* hbB = nullptr;
  unsigned short* hbC = nullptr; unsigned short* hbD = nullptr;
  float* fb_base = nullptr;
  if (use_proj) {
    tokproj = alloc(f_proj);
    descproj = alloc(f_proj);
    float* base2 = alloc(f_mfma);
    cnt      = (unsigned*)base2;                    // 1024 u32
    Bfg_tok  = (unsigned*)(base2 + 1024);           // 524288 u32
    Bfg_desc = (unsigned*)(base2 + 1024 + 524288);
    unsigned short* hb = (unsigned short*)(base2 + 1024 + 2 * 524288);
    hbA = hb; hbB = hb + 262144; hbC = hb + 2 * 262144; hbD = hb + 3 * 262144;
    fb_base = base2;                                // fallback aliases this region
  } else {
    fb_base = alloc(f_fb);
  }
  float* finals  = alloc(2 * BH);
  float* scorep  = alloc(8 * (size_t)BATCH * TCc);
  float* scores  = alloc((size_t)BATCH * TCc);
  float* pooled  = alloc(BH);
  float* a2      = alloc(BH);
  float* code    = alloc(BH);

  float* h_tok0  = fb_base;
  float* c_tok0  = h_tok0 + BH;
  float* h_desc0 = c_tok0 + BH;
  float* c_desc0 = h_desc0 + 2 * BH;
  float* h_tok1  = c_desc0 + 2 * BH;
  float* c_tok1  = h_tok1 + BH;
  float* h_desc1 = c_tok1 + BH;
  float* c_desc1 = h_desc1 + 2 * BH;

  // decide persistent-MFMA availability up front (host-side, synchronous)
  bool mfma_ok = false;
  if (use_proj) {
    hipError_t e = hipFuncSetAttribute((const void*)lstm_persist_kernel,
                                       hipFuncAttributeMaxDynamicSharedMemorySize,
                                       65536 + 17408);
    mfma_ok = (e == hipSuccess);
  }

  if (use_proj) {
    dim3 gp((VOC + 63) / 64, (4 * Hc) / 64);
    gemm64_kernel<0, 0><<<gp, 256, 0, stream>>>(
        tok_emb, tok_Wih, nullptr, tokproj, nullptr, nullptr, VOC, 4 * Hc, Ec);
    gemm64_kernel<0, 0><<<gp, 256, 0, stream>>>(
        desc_emb, desc_Wih, nullptr, descproj, nullptr, nullptr, VOC, 4 * Hc, Ec);
  }

  if (mfma_ok) {
    zero_kernel<<<4, 256, 0, stream>>>((float*)cnt, 1024);
    convert_whh_kernel<<<2048, 256, 0, stream>>>(tok_Whh, Bfg_tok);
    convert_whh_kernel<<<2048, 256, 0, stream>>>(desc_Whh, Bfg_desc);
    PArgs A;
    A.Bfg_tok = Bfg_tok; A.Bfg_desc = Bfg_desc;
    A.tokproj = tokproj; A.descproj = descproj;
    A.tokens = tokens; A.desc_anchor = desc_anchor; A.desc_neg = desc_neg;
    A.desc_anchor_len = desc_anchor_len; A.desc_neg_len = desc_neg_len;
    A.tok_bih = tok_bih; A.tok_bhh = tok_bhh;
    A.desc_bih = desc_bih; A.desc_bhh = desc_bhh;
    A.hA = hbA; A.hB = hbB; A.hC = hbC; A.hD = hbD;
    A.feat = feat; A.finals = finals;
    A.cnt = cnt;
    lstm_persist_kernel<<<256, 256, 65536 + 17408, stream>>>(A);
  } else {
    const int zn = (int)(6 * BH);
    zero_kernel<<<(zn + 255) / 256, 256, 0, stream>>>(h_tok0, zn);
    for (int t = 0; t < TCc; ++t) {
      float* hi = (t & 1) ? h_tok1 : h_tok0;
      float* ho = (t & 1) ? h_tok0 : h_tok1;
      float* ci = (t & 1) ? c_tok1 : c_tok0;
      float* co = (t & 1) ? c_tok0 : c_tok1;
      dim3 g(BATCH / 32, Hc / 16);
      if (use_proj)
        lstm_step2_kernel<1><<<g, 256, 0, stream>>>(
            tokproj, tok_Wih, tokens, nullptr, TCc, t, tok_Whh, tok_bih, tok_bhh,
            hi, ci, ho, co, feat, nullptr, nullptr, nullptr);
      else
        lstm_step2_kernel<0><<<g, 256, 0, stream>>>(
            tok_emb, tok_Wih, tokens, nullptr, TCc, t, tok_Whh, tok_bih, tok_bhh,
            hi, ci, ho, co, feat, nullptr, nullptr, nullptr);
    }
    for (int t = 0; t < TDc; ++t) {
      float* hi = (t & 1) ? h_desc1 : h_desc0;
      float* ho = (t & 1) ? h_desc0 : h_desc1;
      float* ci = (t & 1) ? c_desc1 : c_desc0;
      float* co = (t & 1) ? c_desc0 : c_desc1;
      dim3 g(2 * BATCH / 32, Hc / 16);
      if (use_proj)
        lstm_step2_kernel<1><<<g, 256, 0, stream>>>(
            descproj, desc_Wih, desc_anchor, desc_neg, TDc, t, desc_Whh, desc_bih, desc_bhh,
            hi, ci, ho, co, nullptr, finals, desc_anchor_len, desc_neg_len);
      else
        lstm_step2_kernel<0><<<g, 256, 0, stream>>>(
            desc_emb, desc_Wih, desc_anchor, desc_neg, TDc, t, desc_Whh, desc_bih, desc_bhh,
            hi, ci, ho, co, nullptr, finals, desc_anchor_len, desc_neg_len);
    }
  }

  {
    dim3 ga((BATCH * TCc) / 64, Hc / 64);
    gemm64_kernel<1, 1><<<ga, 256, 0, stream>>>(
        feat, attn_W, attn_b, nullptr, attnS_W, scorep, BATCH * TCc, Hc, Hc);
    score_reduce_kernel<<<(BATCH * TCc + 255) / 256, 256, 0, stream>>>(
        scorep, attnS_b, scores, BATCH * TCc, Hc / 64);
  }

  softmax_pool_kernel<<<BATCH, 256, 0, stream>>>(scores, tok_len, feat, pooled);

  {
    dim3 go(BATCH / 64, Hc / 64);
    gemm64_kernel<1, 0><<<go, 256, 0, stream>>>(
        pooled, out_W1, out_b1, a2, nullptr, nullptr, BATCH, Hc, Hc);
    gemm64_kernel<1, 0><<<go, 256, 0, stream>>>(
        a2, out_W2, out_b2, code, nullptr, nullptr, BATCH, Hc, Hc);
  }

  loss_kernel<<<1, 256, 0, stream>>>(code, finals, (float*)d_out);
}